// Round 1
// baseline (4818.539 us; speedup 1.0000x reference)
//
#include <hip/hip_runtime.h>
#include <math.h>

#define H 70
#define NLAY 4
#define NCLS 10

// ---------------------------------------------------------------- GEMM ----
// Register-blocked fp32 GEMM: Y[M x H] = X[M x K] @ W[K x H] + b, up to 4
// weight sets sharing the X tile (node GEMMs A,B,D,E).
// Thread layout: 16 t-rows x 16 t-cols; each thread computes RM rows x 5 cols.
// TILE_M = 16*RM. Ws padded to 80 cols so tc=15 (cols 75..79) reads stay
// in-bounds (masked at store). K chunked by KC so LDS fits for K=128.
struct GemmMats {
    const float* w[4];
    const float* b[4];
    float* y[4];
};

template <int K, int KC, int RM, int NMAT>
__global__ __launch_bounds__(256) void gemm_kernel(const float* __restrict__ X,
                                                   int M, GemmMats P) {
    constexpr int TM = 16 * RM;
    __shared__ float Xs[TM * (K + 1)];
    __shared__ float Ws[KC * 80];
    const int tid = threadIdx.x;
    const int tc = tid & 15;
    const int tr = tid >> 4;
    const int row0 = blockIdx.x * TM;

    for (int idx = tid; idx < TM * K; idx += 256) {
        int r = idx / K, k = idx - r * K;
        int gr = row0 + r;
        Xs[r * (K + 1) + k] = (gr < M) ? X[(size_t)gr * K + k] : 0.f;
    }
    const int cb = tc * 5;
    for (int m = 0; m < NMAT; ++m) {
        float acc[RM][5];
#pragma unroll
        for (int i = 0; i < RM; ++i)
#pragma unroll
            for (int j = 0; j < 5; ++j) acc[i][j] = 0.f;

        for (int k0 = 0; k0 < K; k0 += KC) {
            __syncthreads();  // protects Xs (first iter) and Ws reuse
            const float* Wm = P.w[m] + k0 * H;
            for (int idx = tid; idx < KC * H; idx += 256) {
                int k = idx / H, c = idx - k * H;
                Ws[k * 80 + c] = Wm[idx];
            }
            __syncthreads();
            for (int k = 0; k < KC; ++k) {
                float w[5];
#pragma unroll
                for (int j = 0; j < 5; ++j) w[j] = Ws[k * 80 + cb + j];
#pragma unroll
                for (int i = 0; i < RM; ++i) {
                    float x = Xs[(tr * RM + i) * (K + 1) + k0 + k];
#pragma unroll
                    for (int j = 0; j < 5; ++j)
                        acc[i][j] = fmaf(x, w[j], acc[i][j]);
                }
            }
        }
        const float* bm = P.b[m];
        float* Ym = P.y[m];
#pragma unroll
        for (int i = 0; i < RM; ++i) {
            int gr = row0 + tr * RM + i;
            if (gr < M) {
#pragma unroll
                for (int j = 0; j < 5; ++j) {
                    int cc = cb + j;
                    if (cc < H) Ym[(size_t)gr * H + cc] = acc[i][j] + bm[cc];
                }
            }
        }
    }
}

// ---------------------------------------------------------------- CSR -----
__global__ void count_deg(const int* __restrict__ dst, int E,
                          int* __restrict__ deg) {
    int e = blockIdx.x * 256 + threadIdx.x;
    if (e < E) atomicAdd(&deg[dst[e]], 1);
}

__global__ __launch_bounds__(256) void scan_phaseA(const int* __restrict__ deg,
                                                   int N, int* __restrict__ bsum) {
    __shared__ int red[256];
    int base = blockIdx.x * 1024;
    int s = 0;
    for (int i = threadIdx.x; i < 1024; i += 256) {
        int g = base + i;
        if (g < N) s += deg[g];
    }
    red[threadIdx.x] = s;
    __syncthreads();
    for (int off = 128; off > 0; off >>= 1) {
        if (threadIdx.x < off) red[threadIdx.x] += red[threadIdx.x + off];
        __syncthreads();
    }
    if (threadIdx.x == 0) bsum[blockIdx.x] = red[0];
}

__global__ void scan_phaseB(const int* __restrict__ bsum, int NB,
                            int* __restrict__ boff, int* __restrict__ rowstart,
                            int N) {
    if (threadIdx.x == 0 && blockIdx.x == 0) {
        int acc = 0;
        for (int i = 0; i < NB; ++i) {
            boff[i] = acc;
            acc += bsum[i];
        }
        rowstart[N] = acc;
    }
}

__global__ __launch_bounds__(256) void scan_phaseC(
    const int* __restrict__ deg, int N, const int* __restrict__ boff,
    int* __restrict__ rowstart, int* __restrict__ cursor) {
    __shared__ int thr[256];
    int base = blockIdx.x * 1024 + threadIdx.x * 4;
    int d[4], loc[4];
    int s = 0;
#pragma unroll
    for (int i = 0; i < 4; ++i) {
        int g = base + i;
        d[i] = (g < N) ? deg[g] : 0;
        loc[i] = s;
        s += d[i];
    }
    thr[threadIdx.x] = s;
    __syncthreads();
    if (threadIdx.x == 0) {
        int a = 0;
        for (int i = 0; i < 256; ++i) {
            int t = thr[i];
            thr[i] = a;
            a += t;
        }
    }
    __syncthreads();
    int off = boff[blockIdx.x] + thr[threadIdx.x];
#pragma unroll
    for (int i = 0; i < 4; ++i) {
        int g = base + i;
        if (g < N) {
            rowstart[g] = off + loc[i];
            cursor[g] = off + loc[i];
        }
    }
}

__global__ void csr_fill(const int* __restrict__ dst, int E,
                         int* __restrict__ cursor, int* __restrict__ eid) {
    int e = blockIdx.x * 256 + threadIdx.x;
    if (e < E) {
        int p = atomicAdd(&cursor[dst[e]], 1);
        eid[p] = e;
    }
}

// ------------------------------------------------------------ edge pass ---
// ehat = Ce + Dh[src] + Eh[dst] (in-place over Ce); accumulate per-channel
// sum/sumsq of (ehat*sne) for edge BN. Grid chosen so stride % 70 == 0:
// each thread owns one fixed channel -> register accumulation.
__global__ __launch_bounds__(256) void edge_kernel(
    float* __restrict__ ehat, const float* __restrict__ Dh,
    const float* __restrict__ Eh, const int* __restrict__ src,
    const int* __restrict__ dst, const float* __restrict__ sne, int E,
    float* __restrict__ esum, float* __restrict__ esq) {
    __shared__ float ls[H], lq[H];
    for (int i = threadIdx.x; i < H; i += 256) {
        ls[i] = 0.f;
        lq[i] = 0.f;
    }
    __syncthreads();
    const int total = E * H;
    const int stride = gridDim.x * 256;  // must be % 70 == 0
    int idx0 = blockIdx.x * 256 + threadIdx.x;
    const int c = idx0 % H;
    float s1 = 0.f, s2 = 0.f;
    for (int idx = idx0; idx < total; idx += stride) {
        int e = idx / H;
        int s = src[e], d = dst[e];
        float v = ehat[idx] + Dh[s * H + c] + Eh[d * H + c];
        ehat[idx] = v;
        float t = v * sne[e];
        s1 += t;
        s2 += t * t;
    }
    atomicAdd(&ls[c], s1);
    atomicAdd(&lq[c], s2);
    __syncthreads();
    for (int i = threadIdx.x; i < H; i += 256) {
        unsafeAtomicAdd(&esum[i], ls[i]);
        unsafeAtomicAdd(&esq[i], lq[i]);
    }
}

__global__ void bn_finalize(const float* __restrict__ stats, float inv_cnt,
                            const float* __restrict__ g,
                            const float* __restrict__ b,
                            float* __restrict__ scale,
                            float* __restrict__ shift) {
    int c = threadIdx.x;
    if (c < H) {
        float m = stats[c] * inv_cnt;
        float v = stats[H + c] * inv_cnt - m * m;
        float rs = rsqrtf(v + 1e-5f);
        float sc = g[c] * rs;
        scale[c] = sc;
        shift[c] = b[c] - m * sc;
    }
}

// io[idx] += relu(pre[idx]*rowscale[row]*scale[c] + shift[c])
__global__ __launch_bounds__(256) void update_kernel(
    float* __restrict__ io, const float* __restrict__ pre,
    const float* __restrict__ rowscale, const float* __restrict__ scale,
    const float* __restrict__ shift, int total) {
    const int stride = gridDim.x * 256;
    for (int idx = blockIdx.x * 256 + threadIdx.x; idx < total; idx += stride) {
        int r = idx / H;
        int c = idx - r * H;
        float t = pre[idx];
        if (rowscale) t *= rowscale[r];
        io[idx] += fmaxf(fmaf(t, scale[c], shift[c]), 0.f);
    }
}

// ------------------------------------------------------- node aggregation -
// Per (node,channel): gather incoming edges via CSR, recompute sigma from
// ehat, num/den, hpre = (Ah + num/(den+1e-6)) * snorm_n. Accumulate h BN
// stats (fixed channel per thread, stride % 70 == 0).
__global__ __launch_bounds__(256) void node_agg(
    const float* __restrict__ ehat, const float* __restrict__ Bh,
    const float* __restrict__ Ah, const int* __restrict__ src,
    const int* __restrict__ rowstart, const int* __restrict__ eid,
    const float* __restrict__ snn, int N, float* __restrict__ hpre,
    float* __restrict__ hsum, float* __restrict__ hsq) {
    __shared__ float ls[H], lq[H];
    for (int i = threadIdx.x; i < H; i += 256) {
        ls[i] = 0.f;
        lq[i] = 0.f;
    }
    __syncthreads();
    const int total = N * H;
    const int stride = gridDim.x * 256;  // must be % 70 == 0
    int idx0 = blockIdx.x * 256 + threadIdx.x;
    const int c = idx0 % H;
    float s1 = 0.f, s2 = 0.f;
    for (int idx = idx0; idx < total; idx += stride) {
        int n = idx / H;
        int p0 = rowstart[n], p1 = rowstart[n + 1];
        float num = 0.f, den = 0.f;
        for (int p = p0; p < p1; ++p) {
            int ed = eid[p];
            float x = ehat[ed * H + c];
            float sg = 1.f / (1.f + __expf(-x));
            den += sg;
            num = fmaf(sg, Bh[src[ed] * H + c], num);
        }
        float val = (Ah[idx] + num / (den + 1e-6f)) * snn[n];
        hpre[idx] = val;
        s1 += val;
        s2 += val * val;
    }
    atomicAdd(&ls[c], s1);
    atomicAdd(&lq[c], s2);
    __syncthreads();
    for (int i = threadIdx.x; i < H; i += 256) {
        unsafeAtomicAdd(&hsum[i], ls[i]);
        unsafeAtomicAdd(&hsq[i], lq[i]);
    }
}

// ---------------------------------------------------------------- readout -
__global__ __launch_bounds__(128) void mlp_readout(
    const float* __restrict__ h, int M, const float* __restrict__ W0,
    const float* __restrict__ b0, const float* __restrict__ W1,
    const float* __restrict__ b1, const float* __restrict__ W2,
    const float* __restrict__ b2, float* __restrict__ out) {
    __shared__ float Hs[128 * 71];
    __shared__ float wbuf[70 * 35 + 35 + 35 * 17 + 17 + 17 * 10 + 10];
    float* sW0 = wbuf;
    float* sb0 = sW0 + 2450;
    float* sW1 = sb0 + 35;
    float* sb1 = sW1 + 595;
    float* sW2 = sb1 + 17;
    float* sb2 = sW2 + 170;
    int tid = threadIdx.x;
    for (int i = tid; i < 2450; i += 128) sW0[i] = W0[i];
    for (int i = tid; i < 35; i += 128) sb0[i] = b0[i];
    for (int i = tid; i < 595; i += 128) sW1[i] = W1[i];
    for (int i = tid; i < 17; i += 128) sb1[i] = b1[i];
    for (int i = tid; i < 170; i += 128) sW2[i] = W2[i];
    for (int i = tid; i < 10; i += 128) sb2[i] = b2[i];
    int row0 = blockIdx.x * 128;
    for (int idx = tid; idx < 128 * H; idx += 128) {
        int r = idx / H, k = idx - r * H;
        int g = row0 + r;
        Hs[r * 71 + k] = (g < M) ? h[(size_t)g * H + k] : 0.f;
    }
    __syncthreads();
    int n = row0 + tid;
    if (n < M) {
        float y0[35];
#pragma unroll
        for (int j = 0; j < 35; ++j) y0[j] = sb0[j];
        for (int k = 0; k < H; ++k) {
            float x = Hs[tid * 71 + k];
#pragma unroll
            for (int j = 0; j < 35; ++j) y0[j] = fmaf(x, sW0[k * 35 + j], y0[j]);
        }
#pragma unroll
        for (int j = 0; j < 35; ++j) y0[j] = fmaxf(y0[j], 0.f);
        float y1[17];
#pragma unroll
        for (int j = 0; j < 17; ++j) y1[j] = sb1[j];
        for (int k = 0; k < 35; ++k) {
            float x = y0[k];
#pragma unroll
            for (int j = 0; j < 17; ++j) y1[j] = fmaf(x, sW1[k * 17 + j], y1[j]);
        }
#pragma unroll
        for (int j = 0; j < 17; ++j) y1[j] = fmaxf(y1[j], 0.f);
        float y2[10];
#pragma unroll
        for (int j = 0; j < 10; ++j) y2[j] = sb2[j];
        for (int k = 0; k < 17; ++k) {
            float x = y1[k];
#pragma unroll
            for (int j = 0; j < 10; ++j) y2[j] = fmaf(x, sW2[k * 10 + j], y2[j]);
        }
#pragma unroll
        for (int j = 0; j < 10; ++j) out[(size_t)n * 10 + j] = y2[j];
    }
}

// ---------------------------------------------------------------- launch --
extern "C" void kernel_launch(void* const* d_in, const int* in_sizes, int n_in,
                              void* d_out, int out_size, void* d_ws,
                              size_t ws_size, hipStream_t stream) {
    const float* in_h = (const float*)d_in[0];
    const float* in_e = (const float*)d_in[1];
    const int* src = (const int*)d_in[2];
    const int* dst = (const int*)d_in[3];
    const float* snn = (const float*)d_in[4];
    const float* sne = (const float*)d_in[5];
    const float* W_eh = (const float*)d_in[6];
    const float* b_eh = (const float*)d_in[7];
    const float* W_ee = (const float*)d_in[8];
    const float* b_ee = (const float*)d_in[9];
    const float* WA = (const float*)d_in[10];
    const float* bA = (const float*)d_in[11];
    const float* WB = (const float*)d_in[12];
    const float* bB = (const float*)d_in[13];
    const float* WC = (const float*)d_in[14];
    const float* bC = (const float*)d_in[15];
    const float* WD = (const float*)d_in[16];
    const float* bD = (const float*)d_in[17];
    const float* WE = (const float*)d_in[18];
    const float* bE = (const float*)d_in[19];
    const float* bnh_g = (const float*)d_in[20];
    const float* bnh_b = (const float*)d_in[21];
    const float* bne_g = (const float*)d_in[22];
    const float* bne_b = (const float*)d_in[23];
    const float* W_m0 = (const float*)d_in[24];
    const float* b_m0 = (const float*)d_in[25];
    const float* W_m1 = (const float*)d_in[26];
    const float* b_m1 = (const float*)d_in[27];
    const float* W_m2 = (const float*)d_in[28];
    const float* b_m2 = (const float*)d_in[29];

    const int N = in_sizes[0] / 128;
    const int E = in_sizes[1] / 128;
    const size_t nh = (size_t)N * H;
    const size_t ne = (size_t)E * H;

    float* p = (float*)d_ws;
    float* h_cur = p;   p += nh;
    float* e_cur = p;   p += ne;
    float* Ah = p;      p += nh;
    float* Bh = p;      p += nh;
    float* Dh = p;      p += nh;   // reused as hpre after K3 consumes Dh
    float* Eh = p;      p += nh;
    float* ehat = p;    p += ne;   // holds Ce, then ehat (in-place)
    float* stats = p;   p += 280;  // esum | esq | hsum | hsq
    float* escale = p;  p += H;
    float* eshift = p;  p += H;
    float* hscale = p;  p += H;
    float* hshift = p;  p += H;
    int* ip = (int*)p;
    int* deg = ip;      ip += N;
    int* rowstart = ip; ip += N + 1;
    int* cursor = ip;   ip += N;
    int* eid = ip;      ip += E;
    int* bsum = ip;     ip += 256;
    int* boff = ip;     ip += 256;
    float* hpre = Dh;

    // ---- CSR build (src/dst constant across layers) ----
    hipMemsetAsync(deg, 0, (size_t)N * sizeof(int), stream);
    count_deg<<<(E + 255) / 256, 256, 0, stream>>>(dst, E, deg);
    const int NB = (N + 1023) / 1024;
    scan_phaseA<<<NB, 256, 0, stream>>>(deg, N, bsum);
    scan_phaseB<<<1, 64, 0, stream>>>(bsum, NB, boff, rowstart, N);
    scan_phaseC<<<NB, 256, 0, stream>>>(deg, N, boff, rowstart, cursor);
    csr_fill<<<(E + 255) / 256, 256, 0, stream>>>(dst, E, cursor, eid);

    // ---- input embeddings (K=128) ----
    GemmMats Ph = {};
    Ph.w[0] = W_eh; Ph.b[0] = b_eh; Ph.y[0] = h_cur;
    gemm_kernel<128, 64, 4, 1><<<(N + 63) / 64, 256, 0, stream>>>(in_h, N, Ph);
    GemmMats Pe = {};
    Pe.w[0] = W_ee; Pe.b[0] = b_ee; Pe.y[0] = e_cur;
    gemm_kernel<128, 64, 4, 1><<<(E + 63) / 64, 256, 0, stream>>>(in_e, E, Pe);

    for (int l = 0; l < NLAY; ++l) {
        GemmMats P4;
        P4.w[0] = WA + l * H * H; P4.b[0] = bA + l * H; P4.y[0] = Ah;
        P4.w[1] = WB + l * H * H; P4.b[1] = bB + l * H; P4.y[1] = Bh;
        P4.w[2] = WD + l * H * H; P4.b[2] = bD + l * H; P4.y[2] = Dh;
        P4.w[3] = WE + l * H * H; P4.b[3] = bE + l * H; P4.y[3] = Eh;
        gemm_kernel<70, 70, 8, 4><<<(N + 127) / 128, 256, 0, stream>>>(h_cur, N, P4);

        GemmMats PC = {};
        PC.w[0] = WC + l * H * H; PC.b[0] = bC + l * H; PC.y[0] = ehat;
        gemm_kernel<70, 70, 8, 1><<<(E + 127) / 128, 256, 0, stream>>>(e_cur, E, PC);

        hipMemsetAsync(stats, 0, 280 * sizeof(float), stream);
        // 1120*256 = 286720 = 70*4096 (stride divisible by 70)
        edge_kernel<<<1120, 256, 0, stream>>>(ehat, Dh, Eh, src, dst, sne, E,
                                              stats, stats + 70);
        bn_finalize<<<1, 128, 0, stream>>>(stats, 1.f / E, bne_g + l * H,
                                           bne_b + l * H, escale, eshift);
        update_kernel<<<4096, 256, 0, stream>>>(e_cur, ehat, sne, escale,
                                                eshift, E * H);
        node_agg<<<1120, 256, 0, stream>>>(ehat, Bh, Ah, src, rowstart, eid,
                                           snn, N, hpre, stats + 140,
                                           stats + 210);
        bn_finalize<<<1, 128, 0, stream>>>(stats + 140, 1.f / N, bnh_g + l * H,
                                           bnh_b + l * H, hscale, hshift);
        update_kernel<<<2048, 256, 0, stream>>>(h_cur, hpre, nullptr, hscale,
                                                hshift, N * H);
    }

    mlp_readout<<<(N + 127) / 128, 128, 0, stream>>>(
        h_cur, N, W_m0, b_m0, W_m1, b_m1, W_m2, b_m2, (float*)d_out);
}

// Round 2
// 3583.327 us; speedup vs baseline: 1.3447x; 1.3447x over previous
//
#include <hip/hip_runtime.h>
#include <math.h>

#define H 70
#define NLAY 4
#define NCLS 10

typedef __attribute__((ext_vector_type(8))) short bf16x8;
typedef __attribute__((ext_vector_type(4))) float f32x4;
typedef __attribute__((ext_vector_type(4))) unsigned int uint4v;
typedef __attribute__((ext_vector_type(4))) int int4v;

struct GemmMats {
    const float* w[4];
    const float* b[4];
    float* y[4];
};

// Split x into hi (truncated bf16) + lo (bf16 of exact remainder); pack two
// consecutive k's bf16 bits into one u32 (k_even in low 16, k_odd in high 16)
// matching the short8 MFMA fragment element order.
__device__ inline unsigned pack_hi16(unsigned u0, unsigned u1) {
    return (u1 & 0xFFFF0000u) | (u0 >> 16);
}
__device__ inline void split_pair(float x0, float x1, unsigned& ph, unsigned& pl) {
    unsigned u0 = __float_as_uint(x0), u1 = __float_as_uint(x1);
    float l0 = x0 - __uint_as_float(u0 & 0xFFFF0000u);  // exact (Sterbenz)
    float l1 = x1 - __uint_as_float(u1 & 0xFFFF0000u);
    ph = pack_hi16(u0, u1);
    pl = pack_hi16(__float_as_uint(l0), __float_as_uint(l1));
}

// ------------------------------------------------------- split-bf16 GEMM --
// Y[M x 70] = X[M x K] @ W[K x 70] + b for up to NMAT weight sets sharing X.
// 3-term split-bf16 MFMA (fp32-class accuracy): Ah*Bh + Al*Bh + Ah*Bl.
// Block = 256 thr = 4 waves; wave w owns rows [blk*64 + w*16, +16).
// A-frags: per-lane global loads (row = lane&15, k = quad*8+j), split in-reg,
// held across mats. W^T split-packed in LDS; B-frag = one ds_read_b128.
template <int K, int NMAT>
__global__ __launch_bounds__(256) void gemm_mfma(const float* __restrict__ X,
                                                 int M, GemmMats P) {
    constexpr int KS = (K + 31) / 32;  // MFMA k-steps (K=70 -> 3, K=128 -> 4)
    constexpr int JK = KS * 16;        // packed u32 (k-pairs) per n-row
    constexpr int SW = JK + 4;         // padded LDS stride (u32), breaks banks
    __shared__ unsigned int Wsh[2 * 80 * SW];  // hi plane | lo plane

    const int tid = threadIdx.x;
    const int wv = tid >> 6;
    const int lane = tid & 63;
    const int mlane = lane & 15;
    const int q = lane >> 4;
    const int rowbase = blockIdx.x * 64 + wv * 16;
    const int rowc = min(rowbase + mlane, M - 1);

    // ---- A fragments (registers, reused across all NMAT) ----
    bf16x8 Ah[KS], Al[KS];
    {
        const float* xr = X + (size_t)rowc * K;
#pragma unroll
        for (int ks = 0; ks < KS; ++ks) {
            int k0 = ks * 32 + q * 8;
            float x[8];
            if (k0 + 8 <= K) {
                float2 p0 = *(const float2*)(xr + k0);
                float2 p1 = *(const float2*)(xr + k0 + 2);
                float2 p2 = *(const float2*)(xr + k0 + 4);
                float2 p3 = *(const float2*)(xr + k0 + 6);
                x[0] = p0.x; x[1] = p0.y; x[2] = p1.x; x[3] = p1.y;
                x[4] = p2.x; x[5] = p2.y; x[6] = p3.x; x[7] = p3.y;
            } else {
#pragma unroll
                for (int j = 0; j < 8; ++j)
                    x[j] = (k0 + j < K) ? xr[k0 + j] : 0.f;
            }
            int4v vh, vl;
            unsigned ph, pl;
            split_pair(x[0], x[1], ph, pl); vh.x = ph; vl.x = pl;
            split_pair(x[2], x[3], ph, pl); vh.y = ph; vl.y = pl;
            split_pair(x[4], x[5], ph, pl); vh.z = ph; vl.z = pl;
            split_pair(x[6], x[7], ph, pl); vh.w = ph; vl.w = pl;
            Ah[ks] = __builtin_bit_cast(bf16x8, vh);
            Al[ks] = __builtin_bit_cast(bf16x8, vl);
        }
    }

    for (int m = 0; m < NMAT; ++m) {
        __syncthreads();  // prior mat's LDS reads done
        const float* Wg = P.w[m];
        for (int idx = tid; idx < 80 * JK; idx += 256) {
            int n = idx / JK, j = idx - n * JK;
            int k0 = 2 * j;
            float w0 = (n < H && k0 < K) ? Wg[k0 * H + n] : 0.f;
            float w1 = (n < H && k0 + 1 < K) ? Wg[(k0 + 1) * H + n] : 0.f;
            unsigned ph, pl;
            split_pair(w0, w1, ph, pl);
            Wsh[n * SW + j] = ph;
            Wsh[80 * SW + n * SW + j] = pl;
        }
        __syncthreads();

        f32x4 acc[5];
#pragma unroll
        for (int nt = 0; nt < 5; ++nt) acc[nt] = {0.f, 0.f, 0.f, 0.f};

#pragma unroll
        for (int ks = 0; ks < KS; ++ks) {
#pragma unroll
            for (int nt = 0; nt < 5; ++nt) {
                int base = (nt * 16 + mlane) * SW + ks * 16 + q * 4;
                uint4v bhv = *(const uint4v*)&Wsh[base];
                uint4v blv = *(const uint4v*)&Wsh[80 * SW + base];
                bf16x8 Bh = __builtin_bit_cast(bf16x8, bhv);
                bf16x8 Bl = __builtin_bit_cast(bf16x8, blv);
                acc[nt] = __builtin_amdgcn_mfma_f32_16x16x32_bf16(Ah[ks], Bh, acc[nt], 0, 0, 0);
                acc[nt] = __builtin_amdgcn_mfma_f32_16x16x32_bf16(Al[ks], Bh, acc[nt], 0, 0, 0);
                acc[nt] = __builtin_amdgcn_mfma_f32_16x16x32_bf16(Ah[ks], Bl, acc[nt], 0, 0, 0);
            }
        }

        const float* bm = P.b[m];
        float* Ym = P.y[m];
#pragma unroll
        for (int nt = 0; nt < 5; ++nt) {
            int col = nt * 16 + mlane;
            if (col < H) {
                float bv = bm[col];
#pragma unroll
                for (int r = 0; r < 4; ++r) {
                    int grow = rowbase + q * 4 + r;
                    if (grow < M)
                        Ym[(size_t)grow * H + col] = acc[nt][r] + bv;
                }
            }
        }
    }
}

// ---------------------------------------------------------------- CSR -----
__global__ void count_deg(const int* __restrict__ dst, int E,
                          int* __restrict__ deg) {
    int e = blockIdx.x * 256 + threadIdx.x;
    if (e < E) atomicAdd(&deg[dst[e]], 1);
}

__global__ __launch_bounds__(256) void scan_phaseA(const int* __restrict__ deg,
                                                   int N, int* __restrict__ bsum) {
    __shared__ int red[256];
    int base = blockIdx.x * 1024;
    int s = 0;
    for (int i = threadIdx.x; i < 1024; i += 256) {
        int g = base + i;
        if (g < N) s += deg[g];
    }
    red[threadIdx.x] = s;
    __syncthreads();
    for (int off = 128; off > 0; off >>= 1) {
        if (threadIdx.x < off) red[threadIdx.x] += red[threadIdx.x + off];
        __syncthreads();
    }
    if (threadIdx.x == 0) bsum[blockIdx.x] = red[0];
}

__global__ void scan_phaseB(const int* __restrict__ bsum, int NB,
                            int* __restrict__ boff, int* __restrict__ rowstart,
                            int N) {
    if (threadIdx.x == 0 && blockIdx.x == 0) {
        int acc = 0;
        for (int i = 0; i < NB; ++i) {
            boff[i] = acc;
            acc += bsum[i];
        }
        rowstart[N] = acc;
    }
}

__global__ __launch_bounds__(256) void scan_phaseC(
    const int* __restrict__ deg, int N, const int* __restrict__ boff,
    int* __restrict__ rowstart, int* __restrict__ cursor) {
    __shared__ int thr[256];
    int base = blockIdx.x * 1024 + threadIdx.x * 4;
    int d[4], loc[4];
    int s = 0;
#pragma unroll
    for (int i = 0; i < 4; ++i) {
        int g = base + i;
        d[i] = (g < N) ? deg[g] : 0;
        loc[i] = s;
        s += d[i];
    }
    thr[threadIdx.x] = s;
    __syncthreads();
    if (threadIdx.x == 0) {
        int a = 0;
        for (int i = 0; i < 256; ++i) {
            int t = thr[i];
            thr[i] = a;
            a += t;
        }
    }
    __syncthreads();
    int off = boff[blockIdx.x] + thr[threadIdx.x];
#pragma unroll
    for (int i = 0; i < 4; ++i) {
        int g = base + i;
        if (g < N) {
            rowstart[g] = off + loc[i];
            cursor[g] = off + loc[i];
        }
    }
}

__global__ void csr_fill(const int* __restrict__ dst, int E,
                         int* __restrict__ cursor, int* __restrict__ eid) {
    int e = blockIdx.x * 256 + threadIdx.x;
    if (e < E) {
        int p = atomicAdd(&cursor[dst[e]], 1);
        eid[p] = e;
    }
}

// ------------------------------------------------------------ edge pass ---
__global__ __launch_bounds__(256) void edge_kernel(
    float* __restrict__ ehat, const float* __restrict__ Dh,
    const float* __restrict__ Eh, const int* __restrict__ src,
    const int* __restrict__ dst, const float* __restrict__ sne, int E,
    float* __restrict__ esum, float* __restrict__ esq) {
    __shared__ float ls[H], lq[H];
    for (int i = threadIdx.x; i < H; i += 256) {
        ls[i] = 0.f;
        lq[i] = 0.f;
    }
    __syncthreads();
    const int total = E * H;
    const int stride = gridDim.x * 256;  // must be % 70 == 0
    int idx0 = blockIdx.x * 256 + threadIdx.x;
    const int c = idx0 % H;
    float s1 = 0.f, s2 = 0.f;
    for (int idx = idx0; idx < total; idx += stride) {
        int e = idx / H;
        int s = src[e], d = dst[e];
        float v = ehat[idx] + Dh[s * H + c] + Eh[d * H + c];
        ehat[idx] = v;
        float t = v * sne[e];
        s1 += t;
        s2 += t * t;
    }
    atomicAdd(&ls[c], s1);
    atomicAdd(&lq[c], s2);
    __syncthreads();
    for (int i = threadIdx.x; i < H; i += 256) {
        unsafeAtomicAdd(&esum[i], ls[i]);
        unsafeAtomicAdd(&esq[i], lq[i]);
    }
}

__global__ void bn_finalize(const float* __restrict__ stats, float inv_cnt,
                            const float* __restrict__ g,
                            const float* __restrict__ b,
                            float* __restrict__ scale,
                            float* __restrict__ shift) {
    int c = threadIdx.x;
    if (c < H) {
        float m = stats[c] * inv_cnt;
        float v = stats[H + c] * inv_cnt - m * m;
        float rs = rsqrtf(v + 1e-5f);
        float sc = g[c] * rs;
        scale[c] = sc;
        shift[c] = b[c] - m * sc;
    }
}

__global__ __launch_bounds__(256) void update_kernel(
    float* __restrict__ io, const float* __restrict__ pre,
    const float* __restrict__ rowscale, const float* __restrict__ scale,
    const float* __restrict__ shift, int total) {
    const int stride = gridDim.x * 256;
    for (int idx = blockIdx.x * 256 + threadIdx.x; idx < total; idx += stride) {
        int r = idx / H;
        int c = idx - r * H;
        float t = pre[idx];
        if (rowscale) t *= rowscale[r];
        io[idx] += fmaxf(fmaf(t, scale[c], shift[c]), 0.f);
    }
}

// ------------------------------------------------------- node aggregation -
__global__ __launch_bounds__(256) void node_agg(
    const float* __restrict__ ehat, const float* __restrict__ Bh,
    const float* __restrict__ Ah, const int* __restrict__ src,
    const int* __restrict__ rowstart, const int* __restrict__ eid,
    const float* __restrict__ snn, int N, float* __restrict__ hpre,
    float* __restrict__ hsum, float* __restrict__ hsq) {
    __shared__ float ls[H], lq[H];
    for (int i = threadIdx.x; i < H; i += 256) {
        ls[i] = 0.f;
        lq[i] = 0.f;
    }
    __syncthreads();
    const int total = N * H;
    const int stride = gridDim.x * 256;  // must be % 70 == 0
    int idx0 = blockIdx.x * 256 + threadIdx.x;
    const int c = idx0 % H;
    float s1 = 0.f, s2 = 0.f;
    for (int idx = idx0; idx < total; idx += stride) {
        int n = idx / H;
        int p0 = rowstart[n], p1 = rowstart[n + 1];
        float num = 0.f, den = 0.f;
        for (int p = p0; p < p1; ++p) {
            int ed = eid[p];
            float x = ehat[ed * H + c];
            float sg = 1.f / (1.f + __expf(-x));
            den += sg;
            num = fmaf(sg, Bh[src[ed] * H + c], num);
        }
        float val = (Ah[idx] + num / (den + 1e-6f)) * snn[n];
        hpre[idx] = val;
        s1 += val;
        s2 += val * val;
    }
    atomicAdd(&ls[c], s1);
    atomicAdd(&lq[c], s2);
    __syncthreads();
    for (int i = threadIdx.x; i < H; i += 256) {
        unsafeAtomicAdd(&hsum[i], ls[i]);
        unsafeAtomicAdd(&hsq[i], lq[i]);
    }
}

// ---------------------------------------------------------------- readout -
__global__ __launch_bounds__(128) void mlp_readout(
    const float* __restrict__ h, int M, const float* __restrict__ W0,
    const float* __restrict__ b0, const float* __restrict__ W1,
    const float* __restrict__ b1, const float* __restrict__ W2,
    const float* __restrict__ b2, float* __restrict__ out) {
    __shared__ float Hs[128 * 71];
    __shared__ float wbuf[70 * 35 + 35 + 35 * 17 + 17 + 17 * 10 + 10];
    float* sW0 = wbuf;
    float* sb0 = sW0 + 2450;
    float* sW1 = sb0 + 35;
    float* sb1 = sW1 + 595;
    float* sW2 = sb1 + 17;
    float* sb2 = sW2 + 170;
    int tid = threadIdx.x;
    for (int i = tid; i < 2450; i += 128) sW0[i] = W0[i];
    for (int i = tid; i < 35; i += 128) sb0[i] = b0[i];
    for (int i = tid; i < 595; i += 128) sW1[i] = W1[i];
    for (int i = tid; i < 17; i += 128) sb1[i] = b1[i];
    for (int i = tid; i < 170; i += 128) sW2[i] = W2[i];
    for (int i = tid; i < 10; i += 128) sb2[i] = b2[i];
    int row0 = blockIdx.x * 128;
    for (int idx = tid; idx < 128 * H; idx += 128) {
        int r = idx / H, k = idx - r * H;
        int g = row0 + r;
        Hs[r * 71 + k] = (g < M) ? h[(size_t)g * H + k] : 0.f;
    }
    __syncthreads();
    int n = row0 + tid;
    if (n < M) {
        float y0[35];
#pragma unroll
        for (int j = 0; j < 35; ++j) y0[j] = sb0[j];
        for (int k = 0; k < H; ++k) {
            float x = Hs[tid * 71 + k];
#pragma unroll
            for (int j = 0; j < 35; ++j) y0[j] = fmaf(x, sW0[k * 35 + j], y0[j]);
        }
#pragma unroll
        for (int j = 0; j < 35; ++j) y0[j] = fmaxf(y0[j], 0.f);
        float y1[17];
#pragma unroll
        for (int j = 0; j < 17; ++j) y1[j] = sb1[j];
        for (int k = 0; k < 35; ++k) {
            float x = y0[k];
#pragma unroll
            for (int j = 0; j < 17; ++j) y1[j] = fmaf(x, sW1[k * 17 + j], y1[j]);
        }
#pragma unroll
        for (int j = 0; j < 17; ++j) y1[j] = fmaxf(y1[j], 0.f);
        float y2[10];
#pragma unroll
        for (int j = 0; j < 10; ++j) y2[j] = sb2[j];
        for (int k = 0; k < 17; ++k) {
            float x = y1[k];
#pragma unroll
            for (int j = 0; j < 10; ++j) y2[j] = fmaf(x, sW2[k * 10 + j], y2[j]);
        }
#pragma unroll
        for (int j = 0; j < 10; ++j) out[(size_t)n * 10 + j] = y2[j];
    }
}

// ---------------------------------------------------------------- launch --
extern "C" void kernel_launch(void* const* d_in, const int* in_sizes, int n_in,
                              void* d_out, int out_size, void* d_ws,
                              size_t ws_size, hipStream_t stream) {
    const float* in_h = (const float*)d_in[0];
    const float* in_e = (const float*)d_in[1];
    const int* src = (const int*)d_in[2];
    const int* dst = (const int*)d_in[3];
    const float* snn = (const float*)d_in[4];
    const float* sne = (const float*)d_in[5];
    const float* W_eh = (const float*)d_in[6];
    const float* b_eh = (const float*)d_in[7];
    const float* W_ee = (const float*)d_in[8];
    const float* b_ee = (const float*)d_in[9];
    const float* WA = (const float*)d_in[10];
    const float* bA = (const float*)d_in[11];
    const float* WB = (const float*)d_in[12];
    const float* bB = (const float*)d_in[13];
    const float* WC = (const float*)d_in[14];
    const float* bC = (const float*)d_in[15];
    const float* WD = (const float*)d_in[16];
    const float* bD = (const float*)d_in[17];
    const float* WE = (const float*)d_in[18];
    const float* bE = (const float*)d_in[19];
    const float* bnh_g = (const float*)d_in[20];
    const float* bnh_b = (const float*)d_in[21];
    const float* bne_g = (const float*)d_in[22];
    const float* bne_b = (const float*)d_in[23];
    const float* W_m0 = (const float*)d_in[24];
    const float* b_m0 = (const float*)d_in[25];
    const float* W_m1 = (const float*)d_in[26];
    const float* b_m1 = (const float*)d_in[27];
    const float* W_m2 = (const float*)d_in[28];
    const float* b_m2 = (const float*)d_in[29];

    const int N = in_sizes[0] / 128;
    const int E = in_sizes[1] / 128;
    const size_t nh = (size_t)N * H;
    const size_t ne = (size_t)E * H;

    float* p = (float*)d_ws;
    float* h_cur = p;   p += nh;
    float* e_cur = p;   p += ne;
    float* Ah = p;      p += nh;
    float* Bh = p;      p += nh;
    float* Dh = p;      p += nh;   // reused as hpre after edge_kernel consumes Dh
    float* Eh = p;      p += nh;
    float* ehat = p;    p += ne;   // holds Ce, then ehat (in-place)
    float* stats = p;   p += 280;  // esum | esq | hsum | hsq
    float* escale = p;  p += H;
    float* eshift = p;  p += H;
    float* hscale = p;  p += H;
    float* hshift = p;  p += H;
    int* ip = (int*)p;
    int* deg = ip;      ip += N;
    int* rowstart = ip; ip += N + 1;
    int* cursor = ip;   ip += N;
    int* eid = ip;      ip += E;
    int* bsum = ip;     ip += 256;
    int* boff = ip;     ip += 256;
    float* hpre = Dh;

    // ---- CSR build ----
    hipMemsetAsync(deg, 0, (size_t)N * sizeof(int), stream);
    count_deg<<<(E + 255) / 256, 256, 0, stream>>>(dst, E, deg);
    const int NB = (N + 1023) / 1024;
    scan_phaseA<<<NB, 256, 0, stream>>>(deg, N, bsum);
    scan_phaseB<<<1, 64, 0, stream>>>(bsum, NB, boff, rowstart, N);
    scan_phaseC<<<NB, 256, 0, stream>>>(deg, N, boff, rowstart, cursor);
    csr_fill<<<(E + 255) / 256, 256, 0, stream>>>(dst, E, cursor, eid);

    // ---- input embeddings (K=128) ----
    GemmMats Ph = {};
    Ph.w[0] = W_eh; Ph.b[0] = b_eh; Ph.y[0] = h_cur;
    gemm_mfma<128, 1><<<(N + 63) / 64, 256, 0, stream>>>(in_h, N, Ph);
    GemmMats Pe = {};
    Pe.w[0] = W_ee; Pe.b[0] = b_ee; Pe.y[0] = e_cur;
    gemm_mfma<128, 1><<<(E + 63) / 64, 256, 0, stream>>>(in_e, E, Pe);

    for (int l = 0; l < NLAY; ++l) {
        GemmMats P4;
        P4.w[0] = WA + l * H * H; P4.b[0] = bA + l * H; P4.y[0] = Ah;
        P4.w[1] = WB + l * H * H; P4.b[1] = bB + l * H; P4.y[1] = Bh;
        P4.w[2] = WD + l * H * H; P4.b[2] = bD + l * H; P4.y[2] = Dh;
        P4.w[3] = WE + l * H * H; P4.b[3] = bE + l * H; P4.y[3] = Eh;
        gemm_mfma<70, 4><<<(N + 63) / 64, 256, 0, stream>>>(h_cur, N, P4);

        GemmMats PC = {};
        PC.w[0] = WC + l * H * H; PC.b[0] = bC + l * H; PC.y[0] = ehat;
        gemm_mfma<70, 1><<<(E + 63) / 64, 256, 0, stream>>>(e_cur, E, PC);

        hipMemsetAsync(stats, 0, 280 * sizeof(float), stream);
        edge_kernel<<<1120, 256, 0, stream>>>(ehat, Dh, Eh, src, dst, sne, E,
                                              stats, stats + 70);
        bn_finalize<<<1, 128, 0, stream>>>(stats, 1.f / E, bne_g + l * H,
                                           bne_b + l * H, escale, eshift);
        update_kernel<<<4096, 256, 0, stream>>>(e_cur, ehat, sne, escale,
                                                eshift, E * H);
        node_agg<<<1120, 256, 0, stream>>>(ehat, Bh, Ah, src, rowstart, eid,
                                           snn, N, hpre, stats + 140,
                                           stats + 210);
        bn_finalize<<<1, 128, 0, stream>>>(stats + 140, 1.f / N, bnh_g + l * H,
                                           bnh_b + l * H, hscale, hshift);
        update_kernel<<<2048, 256, 0, stream>>>(h_cur, hpre, nullptr, hscale,
                                                hshift, N * H);
    }

    mlp_readout<<<(N + 127) / 128, 128, 0, stream>>>(
        h_cur, N, W_m0, b_m0, W_m1, b_m1, W_m2, b_m2, (float*)d_out);
}

// Round 3
// 2894.017 us; speedup vs baseline: 1.6650x; 1.2382x over previous
//
#include <hip/hip_runtime.h>
#include <math.h>

#define H 70
#define NLAY 4
#define NCLS 10

typedef __attribute__((ext_vector_type(8))) short bf16x8;
typedef __attribute__((ext_vector_type(4))) float f32x4;
typedef __attribute__((ext_vector_type(4))) unsigned int uint4v;
typedef __attribute__((ext_vector_type(4))) int int4v;

struct GemmMats {
    const float* w[4];
    const float* b[4];
    float* y[4];
};

__device__ inline unsigned pack_hi16(unsigned u0, unsigned u1) {
    return (u1 & 0xFFFF0000u) | (u0 >> 16);
}
__device__ inline void split_pair(float x0, float x1, unsigned& ph, unsigned& pl) {
    unsigned u0 = __float_as_uint(x0), u1 = __float_as_uint(x1);
    float l0 = x0 - __uint_as_float(u0 & 0xFFFF0000u);  // exact (Sterbenz)
    float l1 = x1 - __uint_as_float(u1 & 0xFFFF0000u);
    ph = pack_hi16(u0, u1);
    pl = pack_hi16(__float_as_uint(l0), __float_as_uint(l1));
}

// Load one 16-row A tile fragment set (split hi/lo) from X (optionally with a
// row permutation). row = rowbase + mlane (clamped), k-chunk = q*8 within each
// 32-wide k-step.
template <int K, int KS>
__device__ inline void load_a_frags(const float* __restrict__ X,
                                    const int* __restrict__ perm, int M,
                                    int rowbase, int mlane, int q,
                                    bf16x8* Ah, bf16x8* Al) {
    int rowc = min(rowbase + mlane, M - 1);
    if (perm) rowc = perm[rowc];
    const float* xr = X + (size_t)rowc * K;
#pragma unroll
    for (int ks = 0; ks < KS; ++ks) {
        int k0 = ks * 32 + q * 8;
        float x[8];
        if (k0 + 8 <= K) {
            float2 p0 = *(const float2*)(xr + k0);
            float2 p1 = *(const float2*)(xr + k0 + 2);
            float2 p2 = *(const float2*)(xr + k0 + 4);
            float2 p3 = *(const float2*)(xr + k0 + 6);
            x[0] = p0.x; x[1] = p0.y; x[2] = p1.x; x[3] = p1.y;
            x[4] = p2.x; x[5] = p2.y; x[6] = p3.x; x[7] = p3.y;
        } else {
#pragma unroll
            for (int j = 0; j < 8; ++j) x[j] = (k0 + j < K) ? xr[k0 + j] : 0.f;
        }
        int4v vh, vl;
        unsigned ph, pl;
        split_pair(x[0], x[1], ph, pl); vh.x = ph; vl.x = pl;
        split_pair(x[2], x[3], ph, pl); vh.y = ph; vl.y = pl;
        split_pair(x[4], x[5], ph, pl); vh.z = ph; vl.z = pl;
        split_pair(x[6], x[7], ph, pl); vh.w = ph; vl.w = pl;
        Ah[ks] = __builtin_bit_cast(bf16x8, vh);
        Al[ks] = __builtin_bit_cast(bf16x8, vl);
    }
}

// Split-pack W[K x 70] (hi|lo planes) into LDS, transposed, k-pairs in u32.
template <int K, int JK, int SW>
__device__ inline void stage_w(const float* __restrict__ Wg, unsigned* Wsh,
                               int tid) {
    for (int idx = tid; idx < 80 * JK; idx += 256) {
        int n = idx / JK, j = idx - n * JK;
        int k0 = 2 * j;
        float w0 = (n < H && k0 < K) ? Wg[k0 * H + n] : 0.f;
        float w1 = (n < H && k0 + 1 < K) ? Wg[(k0 + 1) * H + n] : 0.f;
        unsigned ph, pl;
        split_pair(w0, w1, ph, pl);
        Wsh[n * SW + j] = ph;
        Wsh[80 * SW + n * SW + j] = pl;
    }
}

// ------------------------------------------------------- split-bf16 GEMM --
// Y[M x 70] = X[M x K] @ W[K x 70] + b, NMAT weight sets sharing X.
template <int K, int NMAT>
__global__ __launch_bounds__(256) void gemm_mfma(const float* __restrict__ X,
                                                 const int* __restrict__ perm,
                                                 int M, GemmMats P) {
    constexpr int KS = (K + 31) / 32;
    constexpr int JK = KS * 16;
    constexpr int SW = JK + 4;
    __shared__ unsigned int Wsh[2 * 80 * SW];

    const int tid = threadIdx.x;
    const int wv = tid >> 6;
    const int lane = tid & 63;
    const int mlane = lane & 15;
    const int q = lane >> 4;
    const int rowbase = blockIdx.x * 64 + wv * 16;

    bf16x8 Ah[KS], Al[KS];
    load_a_frags<K, KS>(X, perm, M, rowbase, mlane, q, Ah, Al);

    for (int m = 0; m < NMAT; ++m) {
        __syncthreads();
        stage_w<K, JK, SW>(P.w[m], Wsh, tid);
        __syncthreads();

        f32x4 acc[5];
#pragma unroll
        for (int nt = 0; nt < 5; ++nt) acc[nt] = {0.f, 0.f, 0.f, 0.f};
#pragma unroll
        for (int ks = 0; ks < KS; ++ks) {
#pragma unroll
            for (int nt = 0; nt < 5; ++nt) {
                int base = (nt * 16 + mlane) * SW + ks * 16 + q * 4;
                uint4v bhv = *(const uint4v*)&Wsh[base];
                uint4v blv = *(const uint4v*)&Wsh[80 * SW + base];
                bf16x8 Bhf = __builtin_bit_cast(bf16x8, bhv);
                bf16x8 Blf = __builtin_bit_cast(bf16x8, blv);
                acc[nt] = __builtin_amdgcn_mfma_f32_16x16x32_bf16(Ah[ks], Bhf, acc[nt], 0, 0, 0);
                acc[nt] = __builtin_amdgcn_mfma_f32_16x16x32_bf16(Al[ks], Bhf, acc[nt], 0, 0, 0);
                acc[nt] = __builtin_amdgcn_mfma_f32_16x16x32_bf16(Ah[ks], Blf, acc[nt], 0, 0, 0);
            }
        }
        const float* bm = P.b[m];
        float* Ym = P.y[m];
#pragma unroll
        for (int nt = 0; nt < 5; ++nt) {
            int col = nt * 16 + mlane;
            if (col < H) {
                float bv = bm[col];
#pragma unroll
                for (int r = 0; r < 4; ++r) {
                    int grow = rowbase + q * 4 + r;
                    if (grow < M)
                        Ym[(size_t)grow * H + col] = acc[nt][r] + bv;
                }
            }
        }
    }
}

// ------------------------- fused C-gemm + edge add + e-BN stats (K=70) ----
// ehat[p] = e_cur[p] @ Wc + bc + Dh[src_p[p]] + Eh[dst_p[p]]  (p in CSR order)
// Persistent blocks; W staged once; per-lane BN partials -> 64-copy atomics.
__global__ __launch_bounds__(256) void gemmC_edge(
    const float* __restrict__ Xe, int E, const float* __restrict__ Wg,
    const float* __restrict__ bias, const float* __restrict__ Dh,
    const float* __restrict__ Eh, const int* __restrict__ src_p,
    const int* __restrict__ dst_p, const float* __restrict__ sne_p,
    float* __restrict__ ehat, float* __restrict__ estats) {
    constexpr int K = 70, KS = 3, JK = 48, SW = 52;
    __shared__ unsigned int Wsh[2 * 80 * SW];
    const int tid = threadIdx.x;
    const int wv = tid >> 6;
    const int lane = tid & 63;
    const int mlane = lane & 15;
    const int q = lane >> 4;

    stage_w<K, JK, SW>(Wg, Wsh, tid);
    __syncthreads();

    float bv[5];
#pragma unroll
    for (int nt = 0; nt < 5; ++nt) {
        int col = nt * 16 + mlane;
        bv[nt] = (col < H) ? bias[col] : 0.f;
    }

    float s1[5] = {0.f, 0.f, 0.f, 0.f, 0.f};
    float s2[5] = {0.f, 0.f, 0.f, 0.f, 0.f};

    const int ntiles = (E + 63) / 64;
    for (int tile = blockIdx.x; tile < ntiles; tile += gridDim.x) {
        const int rowbase = tile * 64 + wv * 16;
        bf16x8 Ah[KS], Al[KS];
        load_a_frags<K, KS>(Xe, nullptr, E, rowbase, mlane, q, Ah, Al);

        f32x4 acc[5];
#pragma unroll
        for (int nt = 0; nt < 5; ++nt) acc[nt] = {0.f, 0.f, 0.f, 0.f};
#pragma unroll
        for (int ks = 0; ks < KS; ++ks) {
#pragma unroll
            for (int nt = 0; nt < 5; ++nt) {
                int base = (nt * 16 + mlane) * SW + ks * 16 + q * 4;
                uint4v bhv = *(const uint4v*)&Wsh[base];
                uint4v blv = *(const uint4v*)&Wsh[80 * SW + base];
                bf16x8 Bhf = __builtin_bit_cast(bf16x8, bhv);
                bf16x8 Blf = __builtin_bit_cast(bf16x8, blv);
                acc[nt] = __builtin_amdgcn_mfma_f32_16x16x32_bf16(Ah[ks], Bhf, acc[nt], 0, 0, 0);
                acc[nt] = __builtin_amdgcn_mfma_f32_16x16x32_bf16(Al[ks], Bhf, acc[nt], 0, 0, 0);
                acc[nt] = __builtin_amdgcn_mfma_f32_16x16x32_bf16(Ah[ks], Blf, acc[nt], 0, 0, 0);
            }
        }
        int s4[4], d4[4];
        float sn4[4];
        bool ok4[4];
#pragma unroll
        for (int r = 0; r < 4; ++r) {
            int grow = rowbase + q * 4 + r;
            bool ok = grow < E;
            int gc = ok ? grow : 0;
            s4[r] = src_p[gc];
            d4[r] = dst_p[gc];
            sn4[r] = sne_p[gc];
            ok4[r] = ok;
        }
#pragma unroll
        for (int nt = 0; nt < 5; ++nt) {
            int col = nt * 16 + mlane;
            if (col < H) {
#pragma unroll
                for (int r = 0; r < 4; ++r) {
                    if (ok4[r]) {
                        int grow = rowbase + q * 4 + r;
                        float v = acc[nt][r] + bv[nt] + Dh[s4[r] * H + col] +
                                  Eh[d4[r] * H + col];
                        ehat[(size_t)grow * H + col] = v;
                        float t = v * sn4[r];
                        s1[nt] += t;
                        s2[nt] += t * t;
                    }
                }
            }
        }
    }
    // reduce over quads (rows), then q==0 lanes flush to a stats copy
#pragma unroll
    for (int nt = 0; nt < 5; ++nt) {
        s1[nt] += __shfl_xor(s1[nt], 16);
        s1[nt] += __shfl_xor(s1[nt], 32);
        s2[nt] += __shfl_xor(s2[nt], 16);
        s2[nt] += __shfl_xor(s2[nt], 32);
    }
    if (q == 0) {
        float* buf = estats + (size_t)(blockIdx.x & 63) * 140;
#pragma unroll
        for (int nt = 0; nt < 5; ++nt) {
            int col = nt * 16 + mlane;
            if (col < H) {
                unsafeAtomicAdd(&buf[col], s1[nt]);
                unsafeAtomicAdd(&buf[70 + col], s2[nt]);
            }
        }
    }
}

// ---------------------------------------------------------------- CSR -----
__global__ void count_deg(const int* __restrict__ dst, int E,
                          int* __restrict__ deg) {
    int e = blockIdx.x * 256 + threadIdx.x;
    if (e < E) atomicAdd(&deg[dst[e]], 1);
}

__global__ __launch_bounds__(256) void scan_phaseA(const int* __restrict__ deg,
                                                   int N, int* __restrict__ bsum) {
    __shared__ int red[256];
    int base = blockIdx.x * 1024;
    int s = 0;
    for (int i = threadIdx.x; i < 1024; i += 256) {
        int g = base + i;
        if (g < N) s += deg[g];
    }
    red[threadIdx.x] = s;
    __syncthreads();
    for (int off = 128; off > 0; off >>= 1) {
        if (threadIdx.x < off) red[threadIdx.x] += red[threadIdx.x + off];
        __syncthreads();
    }
    if (threadIdx.x == 0) bsum[blockIdx.x] = red[0];
}

__global__ void scan_phaseB(const int* __restrict__ bsum, int NB,
                            int* __restrict__ boff, int* __restrict__ rowstart,
                            int N) {
    if (threadIdx.x == 0 && blockIdx.x == 0) {
        int acc = 0;
        for (int i = 0; i < NB; ++i) {
            boff[i] = acc;
            acc += bsum[i];
        }
        rowstart[N] = acc;
    }
}

__global__ __launch_bounds__(256) void scan_phaseC(
    const int* __restrict__ deg, int N, const int* __restrict__ boff,
    int* __restrict__ rowstart, int* __restrict__ cursor) {
    __shared__ int thr[256];
    int base = blockIdx.x * 1024 + threadIdx.x * 4;
    int d[4], loc[4];
    int s = 0;
#pragma unroll
    for (int i = 0; i < 4; ++i) {
        int g = base + i;
        d[i] = (g < N) ? deg[g] : 0;
        loc[i] = s;
        s += d[i];
    }
    thr[threadIdx.x] = s;
    __syncthreads();
    if (threadIdx.x == 0) {
        int a = 0;
        for (int i = 0; i < 256; ++i) {
            int t = thr[i];
            thr[i] = a;
            a += t;
        }
    }
    __syncthreads();
    int off = boff[blockIdx.x] + thr[threadIdx.x];
#pragma unroll
    for (int i = 0; i < 4; ++i) {
        int g = base + i;
        if (g < N) {
            rowstart[g] = off + loc[i];
            cursor[g] = off + loc[i];
        }
    }
}

__global__ void csr_fill(const int* __restrict__ dst, int E,
                         int* __restrict__ cursor, int* __restrict__ eid) {
    int e = blockIdx.x * 256 + threadIdx.x;
    if (e < E) {
        int p = atomicAdd(&cursor[dst[e]], 1);
        eid[p] = e;
    }
}

__global__ void perm_build(const int* __restrict__ eid,
                           const int* __restrict__ src,
                           const int* __restrict__ dst,
                           const float* __restrict__ sne, int E,
                           int* __restrict__ src_p, int* __restrict__ dst_p,
                           float* __restrict__ sne_p) {
    int p = blockIdx.x * 256 + threadIdx.x;
    if (p < E) {
        int e = eid[p];
        src_p[p] = src[e];
        dst_p[p] = dst[e];
        sne_p[p] = sne[e];
    }
}

// --------------------------------------------------------------- BN -------
__global__ void bn_finalize_multi(const float* __restrict__ buf, int C,
                                  float inv_cnt, const float* __restrict__ g,
                                  const float* __restrict__ b,
                                  float* __restrict__ scale,
                                  float* __restrict__ shift) {
    __shared__ float red[140];
    int t = threadIdx.x;
    if (t < 140) {
        float s = 0.f;
        for (int i = 0; i < C; ++i) s += buf[(size_t)i * 140 + t];
        red[t] = s;
    }
    __syncthreads();
    if (t < H) {
        float m = red[t] * inv_cnt;
        float v = red[70 + t] * inv_cnt - m * m;
        float rs = rsqrtf(v + 1e-5f);
        float sc = g[t] * rs;
        scale[t] = sc;
        shift[t] = b[t] - m * sc;
    }
}

// ------------------- node aggregation + e-update (CSR-sequential) ---------
__global__ __launch_bounds__(256) void node_agg_fused(
    const float* __restrict__ ehat, const float* __restrict__ Bh,
    const float* __restrict__ Ah, const int* __restrict__ src_p,
    const int* __restrict__ rowstart, const float* __restrict__ snn,
    float* __restrict__ e_cur, const float* __restrict__ sne_p,
    const float* __restrict__ escale, const float* __restrict__ eshift, int N,
    float* __restrict__ hpre, float* __restrict__ hstats) {
    const int total = N * H;
    const int stride = gridDim.x * 256;  // must be % 70 == 0
    int idx0 = blockIdx.x * 256 + threadIdx.x;
    const int c = idx0 % H;
    const float esc = escale[c], esh = eshift[c];
    float s1 = 0.f, s2 = 0.f;
    for (int idx = idx0; idx < total; idx += stride) {
        int n = idx / H;
        int p0 = rowstart[n], p1 = rowstart[n + 1];
        float num = 0.f, den = 0.f;
        for (int p = p0; p < p1; ++p) {
            size_t ei = (size_t)p * H + c;
            float x = ehat[ei];
            float sg = 1.f / (1.f + __expf(-x));
            den += sg;
            int s = src_p[p];
            num = fmaf(sg, Bh[s * H + c], num);
            e_cur[ei] += fmaxf(fmaf(x * sne_p[p], esc, esh), 0.f);
        }
        float val = (Ah[idx] + num / (den + 1e-6f)) * snn[n];
        hpre[idx] = val;
        s1 += val;
        s2 += val * val;
    }
    __shared__ float ls[140];
    for (int i = threadIdx.x; i < 140; i += 256) ls[i] = 0.f;
    __syncthreads();
    atomicAdd(&ls[c], s1);
    atomicAdd(&ls[70 + c], s2);
    __syncthreads();
    float* buf = hstats + (size_t)(blockIdx.x & 15) * 140;
    for (int i = threadIdx.x; i < 140; i += 256) unsafeAtomicAdd(&buf[i], ls[i]);
}

// io[idx] += relu(pre[idx]*scale[c] + shift[c])
__global__ __launch_bounds__(256) void update_h_kernel(
    float* __restrict__ io, const float* __restrict__ pre,
    const float* __restrict__ scale, const float* __restrict__ shift,
    int total) {
    const int stride = gridDim.x * 256;
    for (int idx = blockIdx.x * 256 + threadIdx.x; idx < total; idx += stride) {
        int r = idx / H;
        int c = idx - r * H;
        io[idx] += fmaxf(fmaf(pre[idx], scale[c], shift[c]), 0.f);
    }
}

// ---------------------------------------------------------------- readout -
__global__ __launch_bounds__(128) void mlp_readout(
    const float* __restrict__ h, int M, const float* __restrict__ W0,
    const float* __restrict__ b0, const float* __restrict__ W1,
    const float* __restrict__ b1, const float* __restrict__ W2,
    const float* __restrict__ b2, float* __restrict__ out) {
    __shared__ float Hs[128 * 71];
    __shared__ float wbuf[70 * 35 + 35 + 35 * 17 + 17 + 17 * 10 + 10];
    float* sW0 = wbuf;
    float* sb0 = sW0 + 2450;
    float* sW1 = sb0 + 35;
    float* sb1 = sW1 + 595;
    float* sW2 = sb1 + 17;
    float* sb2 = sW2 + 170;
    int tid = threadIdx.x;
    for (int i = tid; i < 2450; i += 128) sW0[i] = W0[i];
    for (int i = tid; i < 35; i += 128) sb0[i] = b0[i];
    for (int i = tid; i < 595; i += 128) sW1[i] = W1[i];
    for (int i = tid; i < 17; i += 128) sb1[i] = b1[i];
    for (int i = tid; i < 170; i += 128) sW2[i] = W2[i];
    for (int i = tid; i < 10; i += 128) sb2[i] = b2[i];
    int row0 = blockIdx.x * 128;
    for (int idx = tid; idx < 128 * H; idx += 128) {
        int r = idx / H, k = idx - r * H;
        int g = row0 + r;
        Hs[r * 71 + k] = (g < M) ? h[(size_t)g * H + k] : 0.f;
    }
    __syncthreads();
    int n = row0 + tid;
    if (n < M) {
        float y0[35];
#pragma unroll
        for (int j = 0; j < 35; ++j) y0[j] = sb0[j];
        for (int k = 0; k < H; ++k) {
            float x = Hs[tid * 71 + k];
#pragma unroll
            for (int j = 0; j < 35; ++j) y0[j] = fmaf(x, sW0[k * 35 + j], y0[j]);
        }
#pragma unroll
        for (int j = 0; j < 35; ++j) y0[j] = fmaxf(y0[j], 0.f);
        float y1[17];
#pragma unroll
        for (int j = 0; j < 17; ++j) y1[j] = sb1[j];
        for (int k = 0; k < 35; ++k) {
            float x = y0[k];
#pragma unroll
            for (int j = 0; j < 17; ++j) y1[j] = fmaf(x, sW1[k * 17 + j], y1[j]);
        }
#pragma unroll
        for (int j = 0; j < 17; ++j) y1[j] = fmaxf(y1[j], 0.f);
        float y2[10];
#pragma unroll
        for (int j = 0; j < 10; ++j) y2[j] = sb2[j];
        for (int k = 0; k < 17; ++k) {
            float x = y1[k];
#pragma unroll
            for (int j = 0; j < 10; ++j) y2[j] = fmaf(x, sW2[k * 10 + j], y2[j]);
        }
#pragma unroll
        for (int j = 0; j < 10; ++j) out[(size_t)n * 10 + j] = y2[j];
    }
}

// ---------------------------------------------------------------- launch --
extern "C" void kernel_launch(void* const* d_in, const int* in_sizes, int n_in,
                              void* d_out, int out_size, void* d_ws,
                              size_t ws_size, hipStream_t stream) {
    const float* in_h = (const float*)d_in[0];
    const float* in_e = (const float*)d_in[1];
    const int* src = (const int*)d_in[2];
    const int* dst = (const int*)d_in[3];
    const float* snn = (const float*)d_in[4];
    const float* sne = (const float*)d_in[5];
    const float* W_eh = (const float*)d_in[6];
    const float* b_eh = (const float*)d_in[7];
    const float* W_ee = (const float*)d_in[8];
    const float* b_ee = (const float*)d_in[9];
    const float* WA = (const float*)d_in[10];
    const float* bA = (const float*)d_in[11];
    const float* WB = (const float*)d_in[12];
    const float* bB = (const float*)d_in[13];
    const float* WC = (const float*)d_in[14];
    const float* bC = (const float*)d_in[15];
    const float* WD = (const float*)d_in[16];
    const float* bD = (const float*)d_in[17];
    const float* WE = (const float*)d_in[18];
    const float* bE = (const float*)d_in[19];
    const float* bnh_g = (const float*)d_in[20];
    const float* bnh_b = (const float*)d_in[21];
    const float* bne_g = (const float*)d_in[22];
    const float* bne_b = (const float*)d_in[23];
    const float* W_m0 = (const float*)d_in[24];
    const float* b_m0 = (const float*)d_in[25];
    const float* W_m1 = (const float*)d_in[26];
    const float* b_m1 = (const float*)d_in[27];
    const float* W_m2 = (const float*)d_in[28];
    const float* b_m2 = (const float*)d_in[29];

    const int N = in_sizes[0] / 128;
    const int E = in_sizes[1] / 128;
    const size_t nh = (size_t)N * H;
    const size_t ne = (size_t)E * H;

    float* p = (float*)d_ws;
    float* h_cur = p;   p += nh;
    float* e_cur = p;   p += ne;   // permuted (CSR) edge order
    float* Ah = p;      p += nh;
    float* Bh = p;      p += nh;
    float* Dh = p;      p += nh;   // reused as hpre after gemmC_edge consumes Dh
    float* Eh = p;      p += nh;
    float* ehat = p;    p += ne;   // permuted order
    float* stats = p;   p += 80 * 140;  // 64 e-copies | 16 h-copies
    float* escale = p;  p += H;
    float* eshift = p;  p += H;
    float* hscale = p;  p += H;
    float* hshift = p;  p += H;
    float* sne_p = p;   p += E;
    int* ip = (int*)p;
    int* deg = ip;      ip += N;
    int* rowstart = ip; ip += N + 1;
    int* cursor = ip;   ip += N;
    int* eid = ip;      ip += E;
    int* src_p = ip;    ip += E;
    int* dst_p = ip;    ip += E;
    int* bsum = ip;     ip += 256;
    int* boff = ip;     ip += 256;
    float* hpre = Dh;
    float* estats = stats;
    float* hstats = stats + 64 * 140;

    // ---- CSR build + edge permutation ----
    hipMemsetAsync(deg, 0, (size_t)N * sizeof(int), stream);
    count_deg<<<(E + 255) / 256, 256, 0, stream>>>(dst, E, deg);
    const int NB = (N + 1023) / 1024;
    scan_phaseA<<<NB, 256, 0, stream>>>(deg, N, bsum);
    scan_phaseB<<<1, 64, 0, stream>>>(bsum, NB, boff, rowstart, N);
    scan_phaseC<<<NB, 256, 0, stream>>>(deg, N, boff, rowstart, cursor);
    csr_fill<<<(E + 255) / 256, 256, 0, stream>>>(dst, E, cursor, eid);
    perm_build<<<(E + 255) / 256, 256, 0, stream>>>(eid, src, dst, sne, E,
                                                    src_p, dst_p, sne_p);

    // ---- input embeddings (K=128); e embedded directly into CSR order ----
    GemmMats Ph = {};
    Ph.w[0] = W_eh; Ph.b[0] = b_eh; Ph.y[0] = h_cur;
    gemm_mfma<128, 1><<<(N + 63) / 64, 256, 0, stream>>>(in_h, nullptr, N, Ph);
    GemmMats Pe = {};
    Pe.w[0] = W_ee; Pe.b[0] = b_ee; Pe.y[0] = e_cur;
    gemm_mfma<128, 1><<<(E + 63) / 64, 256, 0, stream>>>(in_e, eid, E, Pe);

    for (int l = 0; l < NLAY; ++l) {
        GemmMats P4;
        P4.w[0] = WA + l * H * H; P4.b[0] = bA + l * H; P4.y[0] = Ah;
        P4.w[1] = WB + l * H * H; P4.b[1] = bB + l * H; P4.y[1] = Bh;
        P4.w[2] = WD + l * H * H; P4.b[2] = bD + l * H; P4.y[2] = Dh;
        P4.w[3] = WE + l * H * H; P4.b[3] = bE + l * H; P4.y[3] = Eh;
        gemm_mfma<70, 4><<<(N + 63) / 64, 256, 0, stream>>>(h_cur, nullptr, N, P4);

        hipMemsetAsync(stats, 0, 80 * 140 * sizeof(float), stream);
        gemmC_edge<<<1024, 256, 0, stream>>>(e_cur, E, WC + l * H * H,
                                             bC + l * H, Dh, Eh, src_p, dst_p,
                                             sne_p, ehat, estats);
        bn_finalize_multi<<<1, 256, 0, stream>>>(estats, 64, 1.f / E,
                                                 bne_g + l * H, bne_b + l * H,
                                                 escale, eshift);
        node_agg_fused<<<1120, 256, 0, stream>>>(ehat, Bh, Ah, src_p, rowstart,
                                                 snn, e_cur, sne_p, escale,
                                                 eshift, N, hpre, hstats);
        bn_finalize_multi<<<1, 256, 0, stream>>>(hstats, 16, 1.f / N,
                                                 bnh_g + l * H, bnh_b + l * H,
                                                 hscale, hshift);
        update_h_kernel<<<2048, 256, 0, stream>>>(h_cur, hpre, hscale, hshift,
                                                  N * H);
    }

    mlp_readout<<<(N + 127) / 128, 128, 0, stream>>>(
        h_cur, N, W_m0, b_m0, W_m1, b_m1, W_m2, b_m2, (float*)d_out);
}